// Round 5
// baseline (653.494 us; speedup 1.0000x reference)
//
#include <hip/hip_runtime.h>
#include <hip/hip_bf16.h>

#define S_LEN 2048
#define NHEADS 32
#define NKV 8
#define HD 128
#define QK_SCALE 0.08838834764831845f   // 1/sqrt(128)
#define LOG2E 1.4426950408889634f

#define BQ 64                 // q rows per block
#define BK 32                 // kv rows per tile
#define NQT (S_LEN / BQ)      // 32 q tiles
#define QSTR (NHEADS * HD)    // 4096
#define KSTR (NKV * HD)       // 1024

#define VT_STRIDE 40          // LDS row stride (shorts) for V^T
#define P_STRIDE 40

typedef __attribute__((ext_vector_type(8))) short bf16x8;
typedef __attribute__((ext_vector_type(4))) float f32x4;
typedef __attribute__((ext_vector_type(4))) unsigned u32x4;

__device__ inline unsigned cvt_pk_bf16(float lo, float hi) {
    unsigned r;
    asm("v_cvt_pk_bf16_f32 %0, %1, %2" : "=v"(r) : "v"(lo), "v"(hi));
    return r;
}
__device__ inline short f2bf(float f) {
    unsigned u = __float_as_uint(f);
    u += 0x7fffu + ((u >> 16) & 1u);
    return (short)(u >> 16);
}
__device__ inline bf16x8 as_bf16x8(u32x4 v) {
    union { u32x4 u; bf16x8 b; } c; c.u = v; return c.b;
}

__global__ __launch_bounds__(256, 4) void attn_fwd(
    const float* __restrict__ Q, const float* __restrict__ K,
    const float* __restrict__ V, const float* __restrict__ SL,
    float* __restrict__ O)
{
    const int bx   = blockIdx.x;
    const int h    = bx & (NHEADS - 1);
    const int qt   = (NQT - 1) - (bx >> 5);     // heavy q-tiles dispatch first
    const int kvh  = h >> 2;
    const float slope = SL[h];

    const int tid  = threadIdx.x;
    const int w    = tid >> 6;
    const int lane = tid & 63;
    const int l16  = lane & 15;
    const int lq   = lane >> 4;

    __shared__ short VTs[2][HD * VT_STRIDE];   // double-buffered V^T [d][k]
    __shared__ short Ps[4][16 * P_STRIDE];     // per-wave P [q][k]

    const int qrow0 = qt * BQ + w * 16;

    // ---- Q fragments (A-operand: row=l16, k=8*lq+j) ----
    bf16x8 qf[4];
    {
        const float* qp = Q + (size_t)(qrow0 + l16) * QSTR + h * HD + lq * 8;
        #pragma unroll
        for (int d0 = 0; d0 < 4; ++d0) {
            f32x4 a = *(const f32x4*)(qp + d0 * 32);
            f32x4 b = *(const f32x4*)(qp + d0 * 32 + 4);
            u32x4 t;
            t[0] = cvt_pk_bf16(a[0], a[1]); t[1] = cvt_pk_bf16(a[2], a[3]);
            t[2] = cvt_pk_bf16(b[0], b[1]); t[3] = cvt_pk_bf16(b[2], b[3]);
            qf[d0] = as_bf16x8(t);
        }
    }
    // all-ones B fragment for P row-sum MFMA
    bf16x8 onesf;
    #pragma unroll
    for (int j = 0; j < 8; ++j) onesf[j] = (short)0x3f80;

    f32x4 acc[8];
    #pragma unroll
    for (int t = 0; t < 8; ++t) acc[t] = (f32x4){0.f, 0.f, 0.f, 0.f};
    float m_i[4] = {-1e30f, -1e30f, -1e30f, -1e30f};
    float l_i[4] = {0.f, 0.f, 0.f, 0.f};

    // per-row constants for ALiBi fma-fold
    float sqf[4];    // slope * qrow_i
    int   qri[4];
    #pragma unroll
    for (int i = 0; i < 4; ++i) {
        qri[i] = qrow0 + 4 * lq + i;
        sqf[i] = slope * (float)qri[i];
    }

    const int kv_end = qt * BQ + BQ;

    // ---- ALiBi far-tile skip (weight <= e^-33 vs diagonal) ----
    int kb_start = 0;
    {
        float thresh = (float)(qt * BQ) - 31.0f - 45.0f / slope;
        int t = (int)floorf(thresh);
        kb_start = (t < 0) ? 0 : (((t >> 5) + 1) << 5);
    }

    // ---- V staging mapping: col d = vd, 8 consecutive k per thread ----
    const int vd  = tid & 127, vrb = (tid >> 7) * 8;
    const float* Vbase = V + (size_t)kvh * HD + vd;

    float vr[2][8];

    auto load_vregs = [&](int kb) {
        #pragma unroll
        for (int s = 0; s < 2; ++s)
            #pragma unroll
            for (int j = 0; j < 8; ++j)
                vr[s][j] = Vbase[(size_t)(kb + vrb + s * 16 + j) * KSTR];
    };
    auto store_vtile = [&](int b) {
        #pragma unroll
        for (int s = 0; s < 2; ++s) {
            u32x4 t;
            t[0] = cvt_pk_bf16(vr[s][0], vr[s][1]);
            t[1] = cvt_pk_bf16(vr[s][2], vr[s][3]);
            t[2] = cvt_pk_bf16(vr[s][4], vr[s][5]);
            t[3] = cvt_pk_bf16(vr[s][6], vr[s][7]);
            *(u32x4*)&VTs[b][vd * VT_STRIDE + vrb + s * 16] = t;
        }
    };

    // prologue: stage first V tile into buffer 0
    load_vregs(kb_start);
    store_vtile(0);
    int cur = 0;

    // K direct-load base (per-lane): row kb+l16 (+16), cols d0*32 + lq*8
    const float* Kcol = K + (size_t)kvh * HD + lq * 8;

    for (int kb = kb_start; kb < kv_end; kb += BK) {
        // one barrier per tile; vmcnt NOT drained (V prefetch spans barrier)
        asm volatile("s_waitcnt lgkmcnt(0)\n\ts_barrier" ::: "memory");

        const bool has_next = (kb + BK) < kv_end;
        if (has_next) load_vregs(kb + BK);   // global V loads in flight across compute

        const bool live = (kb <= qrow0 + 15) &&
                          (slope * (float)(qrow0 - kb - 31) < 45.0f);
        if (live) {
            const short* Vc = &VTs[cur][0];
            const float* krow0 = Kcol + (size_t)(kb + l16) * KSTR;
            const float* krow1 = krow0 + (size_t)16 * KSTR;

            // ---- QK^T with K B-fragments loaded directly from global ----
            f32x4 sc0 = (f32x4){0.f,0.f,0.f,0.f};
            f32x4 sc1 = (f32x4){0.f,0.f,0.f,0.f};
            #pragma unroll
            for (int d0 = 0; d0 < 4; ++d0) {
                f32x4 a0 = *(const f32x4*)(krow0 + d0 * 32);
                f32x4 b0 = *(const f32x4*)(krow0 + d0 * 32 + 4);
                f32x4 a1 = *(const f32x4*)(krow1 + d0 * 32);
                f32x4 b1 = *(const f32x4*)(krow1 + d0 * 32 + 4);
                u32x4 t0, t1;
                t0[0] = cvt_pk_bf16(a0[0], a0[1]); t0[1] = cvt_pk_bf16(a0[2], a0[3]);
                t0[2] = cvt_pk_bf16(b0[0], b0[1]); t0[3] = cvt_pk_bf16(b0[2], b0[3]);
                t1[0] = cvt_pk_bf16(a1[0], a1[1]); t1[1] = cvt_pk_bf16(a1[2], a1[3]);
                t1[2] = cvt_pk_bf16(b1[0], b1[1]); t1[3] = cvt_pk_bf16(b1[2], b1[3]);
                sc0 = __builtin_amdgcn_mfma_f32_16x16x32_bf16(qf[d0], as_bf16x8(t0), sc0, 0, 0, 0);
                sc1 = __builtin_amdgcn_mfma_f32_16x16x32_bf16(qf[d0], as_bf16x8(t1), sc1, 0, 0, 0);
            }

            // ---- scale + ALiBi (fma-fold) + causal ----
            const int   kc0  = kb + l16, kc1 = kb + 16 + l16;
            const float kcf0 = (float)kc0, kcf1 = (float)kc1;
            float s0v[4], s1v[4], lm[4];
            bool need = false;
            #pragma unroll
            for (int i = 0; i < 4; ++i) {
                float ab0 = __builtin_fmaf(slope, kcf0, -sqf[i]);
                float ab1 = __builtin_fmaf(slope, kcf1, -sqf[i]);
                float s0 = (kc0 > qri[i]) ? -1e30f
                         : __builtin_fmaf(sc0[i], QK_SCALE, ab0);
                float s1 = (kc1 > qri[i]) ? -1e30f
                         : __builtin_fmaf(sc1[i], QK_SCALE, ab1);
                s0v[i] = s0; s1v[i] = s1;
                lm[i] = fmaxf(s0, s1);
                need = need || (lm[i] > m_i[i] + 8.0f);
            }
            // ---- defer-max: full reduce + rescale only on growth (rare) ----
            if (__any(need)) {
                #pragma unroll
                for (int i = 0; i < 4; ++i) {
                    float rm = lm[i];
                    rm = fmaxf(rm, __shfl_xor(rm, 1));
                    rm = fmaxf(rm, __shfl_xor(rm, 2));
                    rm = fmaxf(rm, __shfl_xor(rm, 4));
                    rm = fmaxf(rm, __shfl_xor(rm, 8));
                    if (rm > m_i[i] + 8.0f) {
                        float alpha = exp2f((m_i[i] - rm) * LOG2E);
                        m_i[i] = rm;
                        l_i[i] *= alpha;
                        #pragma unroll
                        for (int t = 0; t < 8; ++t) acc[t][i] *= alpha;
                    }
                }
            }

            // ---- P = exp2(s - m), commit to bf16 via LDS round trip ----
            short* PsW = &Ps[w][0];
            #pragma unroll
            for (int i = 0; i < 4; ++i) {
                float p0 = exp2f((s0v[i] - m_i[i]) * LOG2E);
                float p1 = exp2f((s1v[i] - m_i[i]) * LOG2E);
                PsW[(4 * lq + i) * P_STRIDE + l16]      = f2bf(p0);
                PsW[(4 * lq + i) * P_STRIDE + 16 + l16] = f2bf(p1);
            }
            asm volatile("s_waitcnt lgkmcnt(0)" ::: "memory");
            bf16x8 pf = *(const bf16x8*)&PsW[l16 * P_STRIDE + lq * 8];

            // ---- row-sum of P via ones-MFMA ----
            f32x4 sums = (f32x4){0.f,0.f,0.f,0.f};
            sums = __builtin_amdgcn_mfma_f32_16x16x32_bf16(pf, onesf, sums, 0, 0, 0);

            // ---- PV ----
            #pragma unroll
            for (int nt = 0; nt < 8; ++nt) {
                bf16x8 vf = *(const bf16x8*)&Vc[(nt * 16 + l16) * VT_STRIDE + lq * 8];
                acc[nt] = __builtin_amdgcn_mfma_f32_16x16x32_bf16(pf, vf, acc[nt], 0, 0, 0);
            }
            #pragma unroll
            for (int i = 0; i < 4; ++i) l_i[i] += sums[i];
        }

        if (has_next) store_vtile(cur ^ 1);  // fill other buffer while others compute
        cur ^= 1;
    }

    // ---- epilogue ----
    #pragma unroll
    for (int i = 0; i < 4; ++i) {
        float rl = 1.0f / l_i[i];
        const size_t row = (size_t)qri[i];
        float* op = O + row * QSTR + h * HD + l16;
        #pragma unroll
        for (int nt = 0; nt < 8; ++nt)
            op[nt * 16] = acc[nt][i] * rl;
    }
}

extern "C" void kernel_launch(void* const* d_in, const int* in_sizes, int n_in,
                              void* d_out, int out_size, void* d_ws, size_t ws_size,
                              hipStream_t stream) {
    const float* Q  = (const float*)d_in[0];
    const float* K  = (const float*)d_in[1];
    const float* V  = (const float*)d_in[2];
    const float* SL = (const float*)d_in[3];
    float* O = (float*)d_out;

    dim3 grid(NQT * NHEADS);
    dim3 block(256);
    attn_fwd<<<grid, block, 0, stream>>>(Q, K, V, SL, O);
}

// Round 8
// 271.764 us; speedup vs baseline: 2.4046x; 2.4046x over previous
//
#include <hip/hip_runtime.h>
#include <hip/hip_bf16.h>

#define S_LEN 2048
#define NHEADS 32
#define NKV 8
#define HD 128
#define QK_SCALE 0.08838834764831845f           // 1/sqrt(128)
#define LOG2E 1.4426950408889634f
#define QK_SCALE2 (QK_SCALE * LOG2E)            // fold into Q (log2 domain)
#define DTHR 11.5416f                           // defer-max threshold, 8 nats in log2

#define BQ 64                 // q rows per block (4 waves x 16)
#define BK 32                 // kv rows per tile
#define NQT (S_LEN / BQ)      // 32 q tiles
#define QSTR (NHEADS * HD)    // 4096
#define KSTR (NKV * HD)       // 1024
#define P_STRIDE 40

typedef __attribute__((ext_vector_type(8))) short bf16x8;
typedef __attribute__((ext_vector_type(4))) float f32x4;
typedef __attribute__((ext_vector_type(4))) unsigned u32x4;

__device__ inline unsigned cvt_pk_bf16(float lo, float hi) {
    unsigned r;
    asm("v_cvt_pk_bf16_f32 %0, %1, %2" : "=v"(r) : "v"(lo), "v"(hi));
    return r;
}
__device__ inline short f2bf(float f) {
    unsigned u = __float_as_uint(f);
    u += 0x7fffu + ((u >> 16) & 1u);
    return (short)(u >> 16);
}
__device__ inline bf16x8 as_bf16x8(u32x4 v) {
    union { u32x4 u; bf16x8 b; } c; c.u = v; return c.b;
}

// ---- pre-pass 1: K [s][kv*hd] f32 -> Kbf [kv][s][hd] bf16 (fragment-ready) ----
__global__ __launch_bounds__(256) void prep_k(const float* __restrict__ K,
                                              short* __restrict__ Kbf) {
    int g = blockIdx.x * 256 + threadIdx.x;     // [0, S*KV*16)
    int chunk = g & 15, kvh = (g >> 4) & 7, s = g >> 7;
    const float* in = K + (size_t)s * KSTR + kvh * HD + chunk * 8;
    f32x4 a = *(const f32x4*)in;
    f32x4 b = *(const f32x4*)(in + 4);
    u32x4 t;
    t[0] = cvt_pk_bf16(a[0], a[1]); t[1] = cvt_pk_bf16(a[2], a[3]);
    t[2] = cvt_pk_bf16(b[0], b[1]); t[3] = cvt_pk_bf16(b[2], b[3]);
    *(u32x4*)(Kbf + ((size_t)kvh * S_LEN + s) * HD + chunk * 8) = t;
}

// ---- pre-pass 2: V [s][kv*hd] f32 -> Vtb [kv][hd][s] bf16 (transposed) ----
// R7 bug fixed here: each thread gathers 16 elements and must store BOTH
// u32x4 halves (R6/R7 stored only tmp[0..7] -> half of Vtb stayed poisoned).
__global__ __launch_bounds__(256) void prep_v(const float* __restrict__ V,
                                              short* __restrict__ Vtb) {
    __shared__ short Ts[64][72];                 // 144B row stride: 16B-aligned
    int b = blockIdx.x;                          // 512 = kvh(8) x db(2) x sb(32)
    int sb = b & 31, db = (b >> 5) & 1, kvh = b >> 6;
    int t = threadIdx.x, r = t >> 2, c0 = (t & 3) * 16;

    const float* in = V + (size_t)(sb * 64 + r) * KSTR + kvh * HD + db * 64 + c0;
    f32x4 a0 = *(const f32x4*)in,        a1 = *(const f32x4*)(in + 4);
    f32x4 a2 = *(const f32x4*)(in + 8),  a3 = *(const f32x4*)(in + 12);
    u32x4 t0;
    t0[0] = cvt_pk_bf16(a0[0], a0[1]); t0[1] = cvt_pk_bf16(a0[2], a0[3]);
    t0[2] = cvt_pk_bf16(a1[0], a1[1]); t0[3] = cvt_pk_bf16(a1[2], a1[3]);
    *(u32x4*)&Ts[r][c0] = t0;
    t0[0] = cvt_pk_bf16(a2[0], a2[1]); t0[1] = cvt_pk_bf16(a2[2], a2[3]);
    t0[2] = cvt_pk_bf16(a3[0], a3[1]); t0[3] = cvt_pk_bf16(a3[2], a3[3]);
    *(u32x4*)&Ts[r][c0 + 8] = t0;
    __syncthreads();

    alignas(16) short tmp[16];
    #pragma unroll
    for (int j = 0; j < 16; ++j) tmp[j] = Ts[c0 + j][r];
    short* dst = Vtb + ((size_t)(kvh * HD + db * 64 + r)) * S_LEN + sb * 64 + c0;
    *(u32x4*)dst       = *(u32x4*)&tmp[0];
    *(u32x4*)(dst + 8) = *(u32x4*)&tmp[8];
}

// ---- main: barrier-free flash attention, K/V fragments direct from bf16 ----
__global__ __launch_bounds__(256) void attn_fwd(
    const float* __restrict__ Q, const short* __restrict__ Kbf,
    const short* __restrict__ Vtb, const float* __restrict__ SL,
    float* __restrict__ O)
{
    const int bx   = blockIdx.x;
    const int h    = bx & (NHEADS - 1);
    const int qt   = (NQT - 1) - (bx >> 5);     // heavy q-tiles first
    const int kvh  = h >> 2;
    const float slope  = SL[h];
    const float slope2 = slope * LOG2E;

    const int tid  = threadIdx.x;
    const int w    = tid >> 6;
    const int lane = tid & 63;
    const int l16  = lane & 15;
    const int lq   = lane >> 4;

    __shared__ short Ps[4][16 * P_STRIDE];      // per-wave P [q][k], wave-local

    const int qrow0 = qt * BQ + w * 16;

    // ---- Q fragments, scale*log2e folded in ----
    bf16x8 qf[4];
    {
        const float* qp = Q + (size_t)(qrow0 + l16) * QSTR + h * HD + lq * 8;
        #pragma unroll
        for (int d0 = 0; d0 < 4; ++d0) {
            f32x4 a = *(const f32x4*)(qp + d0 * 32);
            f32x4 b = *(const f32x4*)(qp + d0 * 32 + 4);
            u32x4 t;
            t[0] = cvt_pk_bf16(a[0] * QK_SCALE2, a[1] * QK_SCALE2);
            t[1] = cvt_pk_bf16(a[2] * QK_SCALE2, a[3] * QK_SCALE2);
            t[2] = cvt_pk_bf16(b[0] * QK_SCALE2, b[1] * QK_SCALE2);
            t[3] = cvt_pk_bf16(b[2] * QK_SCALE2, b[3] * QK_SCALE2);
            qf[d0] = as_bf16x8(t);
        }
    }
    bf16x8 onesf;
    #pragma unroll
    for (int j = 0; j < 8; ++j) onesf[j] = (short)0x3f80;

    f32x4 acc[8];
    #pragma unroll
    for (int t = 0; t < 8; ++t) acc[t] = (f32x4){0.f, 0.f, 0.f, 0.f};
    float m_i[4] = {-1e30f, -1e30f, -1e30f, -1e30f};
    float l_i[4] = {0.f, 0.f, 0.f, 0.f};

    float sq2[4];                                // slope2 * qrow_i
    int   qri[4];
    #pragma unroll
    for (int i = 0; i < 4; ++i) {
        qri[i] = qrow0 + 4 * lq + i;
        sq2[i] = slope2 * (float)qri[i];
    }

    // ---- per-wave loop bounds: causal end + ALiBi start ----
    const int kbe = qrow0 + 16;                  // exclusive
    int kbs = 0;
    {
        float th = (float)qrow0 - 31.0f - 45.0f / slope;
        int t = (int)floorf(th);
        kbs = (t < 0) ? 0 : (((t >> 5) + 1) << 5);
    }

    // per-lane fragment bases
    const short* Kfb = Kbf + ((size_t)kvh * S_LEN + l16) * HD + lq * 8;
    const short* Vfb = Vtb + ((size_t)kvh * HD + l16) * S_LEN + lq * 8;
    short* PsW = &Ps[w][0];

    for (int kb = kbs; kb < kbe; kb += BK) {
        // ---- QK^T: K B-fragments straight from global bf16 ----
        const short* kp0 = Kfb + (size_t)kb * HD;
        f32x4 sc0 = (f32x4){0.f,0.f,0.f,0.f};
        f32x4 sc1 = (f32x4){0.f,0.f,0.f,0.f};
        #pragma unroll
        for (int d0 = 0; d0 < 4; ++d0) {
            bf16x8 kf0 = *(const bf16x8*)(kp0 + d0 * 32);
            bf16x8 kf1 = *(const bf16x8*)(kp0 + 16 * HD + d0 * 32);
            sc0 = __builtin_amdgcn_mfma_f32_16x16x32_bf16(qf[d0], kf0, sc0, 0, 0, 0);
            sc1 = __builtin_amdgcn_mfma_f32_16x16x32_bf16(qf[d0], kf1, sc1, 0, 0, 0);
        }

        // ---- V fragments prefetch (independent of P; hides L2 latency) ----
        bf16x8 vfr[8];
        #pragma unroll
        for (int nt = 0; nt < 8; ++nt)
            vfr[nt] = *(const bf16x8*)(Vfb + (size_t)nt * 16 * S_LEN + kb);

        // ---- bias + causal (log2 domain) ----
        const int   kc0  = kb + l16, kc1 = kb + 16 + l16;
        const float kcf0 = (float)kc0, kcf1 = (float)kc1;
        float s0v[4], s1v[4], lm[4];
        bool need = false;
        #pragma unroll
        for (int i = 0; i < 4; ++i) {
            float s0 = (kc0 > qri[i]) ? -1e30f
                     : sc0[i] + __builtin_fmaf(slope2, kcf0, -sq2[i]);
            float s1 = (kc1 > qri[i]) ? -1e30f
                     : sc1[i] + __builtin_fmaf(slope2, kcf1, -sq2[i]);
            s0v[i] = s0; s1v[i] = s1;
            lm[i] = fmaxf(s0, s1);
            need = need || (lm[i] > m_i[i] + DTHR);
        }
        // ---- defer-max: reduce + rescale only on growth ----
        if (__any(need)) {
            #pragma unroll
            for (int i = 0; i < 4; ++i) {
                float rm = lm[i];
                rm = fmaxf(rm, __shfl_xor(rm, 1));
                rm = fmaxf(rm, __shfl_xor(rm, 2));
                rm = fmaxf(rm, __shfl_xor(rm, 4));
                rm = fmaxf(rm, __shfl_xor(rm, 8));
                if (rm > m_i[i] + DTHR) {
                    float alpha = exp2f(m_i[i] - rm);
                    m_i[i] = rm;
                    l_i[i] *= alpha;
                    #pragma unroll
                    for (int t = 0; t < 8; ++t) acc[t][i] *= alpha;
                }
            }
        }

        // ---- P = exp2(s - m), bf16 via wave-local LDS (layout C->A) ----
        #pragma unroll
        for (int i = 0; i < 4; ++i) {
            float p0 = exp2f(s0v[i] - m_i[i]);
            float p1 = exp2f(s1v[i] - m_i[i]);
            PsW[(4 * lq + i) * P_STRIDE + l16]      = f2bf(p0);
            PsW[(4 * lq + i) * P_STRIDE + 16 + l16] = f2bf(p1);
        }
        // fence: scalar-short stores vs vector read have distinct TBAA
        asm volatile("s_waitcnt lgkmcnt(0)" ::: "memory");
        __builtin_amdgcn_sched_barrier(0);
        bf16x8 pf = *(const bf16x8*)&PsW[l16 * P_STRIDE + lq * 8];

        // ---- row-sum via ones-MFMA, then PV ----
        f32x4 sums = (f32x4){0.f,0.f,0.f,0.f};
        sums = __builtin_amdgcn_mfma_f32_16x16x32_bf16(pf, onesf, sums, 0, 0, 0);
        #pragma unroll
        for (int nt = 0; nt < 8; ++nt)
            acc[nt] = __builtin_amdgcn_mfma_f32_16x16x32_bf16(pf, vfr[nt], acc[nt], 0, 0, 0);
        #pragma unroll
        for (int i = 0; i < 4; ++i) l_i[i] += sums[i];
    }

    // ---- epilogue ----
    #pragma unroll
    for (int i = 0; i < 4; ++i) {
        float rl = 1.0f / l_i[i];
        float* op = O + (size_t)qri[i] * QSTR + h * HD + l16;
        #pragma unroll
        for (int nt = 0; nt < 8; ++nt)
            op[nt * 16] = acc[nt][i] * rl;
    }
}

extern "C" void kernel_launch(void* const* d_in, const int* in_sizes, int n_in,
                              void* d_out, int out_size, void* d_ws, size_t ws_size,
                              hipStream_t stream) {
    const float* Q  = (const float*)d_in[0];
    const float* K  = (const float*)d_in[1];
    const float* V  = (const float*)d_in[2];
    const float* SL = (const float*)d_in[3];
    float* O = (float*)d_out;

    short* Kbf = (short*)d_ws;                                   // 4 MB
    short* Vtb = (short*)d_ws + (size_t)NKV * S_LEN * HD;        // 4 MB

    prep_k<<<dim3(1024), dim3(256), 0, stream>>>(K, Kbf);
    prep_v<<<dim3(512),  dim3(256), 0, stream>>>(V, Vtb);
    attn_fwd<<<dim3(NQT * NHEADS), dim3(256), 0, stream>>>(Q, Kbf, Vtb, SL, O);
}

// Round 9
// 256.323 us; speedup vs baseline: 2.5495x; 1.0602x over previous
//
#include <hip/hip_runtime.h>
#include <hip/hip_bf16.h>

#define S_LEN 2048
#define NHEADS 32
#define NKV 8
#define HD 128
#define QK_SCALE 0.08838834764831845f           // 1/sqrt(128)
#define LOG2E 1.4426950408889634f
#define QK_SCALE2 (QK_SCALE * LOG2E)            // fold into Q (log2 domain)
#define DTHR 11.5416f                           // defer-max threshold, 8 nats in log2

#define BK 32                 // kv rows per tile
#define NQP (S_LEN / 16)      // 128 q-positions (16 rows per wave)
#define QSTR (NHEADS * HD)    // 4096
#define KSTR (NKV * HD)       // 1024
#define P_STRIDE 40

typedef __attribute__((ext_vector_type(8))) short bf16x8;
typedef __attribute__((ext_vector_type(4))) float f32x4;
typedef __attribute__((ext_vector_type(4))) unsigned u32x4;

__device__ inline unsigned cvt_pk_bf16(float lo, float hi) {
    unsigned r;
    asm("v_cvt_pk_bf16_f32 %0, %1, %2" : "=v"(r) : "v"(lo), "v"(hi));
    return r;
}
__device__ inline short f2bf(float f) {
    unsigned u = __float_as_uint(f);
    u += 0x7fffu + ((u >> 16) & 1u);
    return (short)(u >> 16);
}
__device__ inline bf16x8 as_bf16x8(u32x4 v) {
    union { u32x4 u; bf16x8 b; } c; c.u = v; return c.b;
}

// ---- pre-pass 1: K [s][kv*hd] f32 -> Kbf [kv][s][hd] bf16 (fragment-ready) ----
__global__ __launch_bounds__(256) void prep_k(const float* __restrict__ K,
                                              short* __restrict__ Kbf) {
    int g = blockIdx.x * 256 + threadIdx.x;     // [0, S*KV*16)
    int chunk = g & 15, kvh = (g >> 4) & 7, s = g >> 7;
    const float* in = K + (size_t)s * KSTR + kvh * HD + chunk * 8;
    f32x4 a = *(const f32x4*)in;
    f32x4 b = *(const f32x4*)(in + 4);
    u32x4 t;
    t[0] = cvt_pk_bf16(a[0], a[1]); t[1] = cvt_pk_bf16(a[2], a[3]);
    t[2] = cvt_pk_bf16(b[0], b[1]); t[3] = cvt_pk_bf16(b[2], b[3]);
    *(u32x4*)(Kbf + ((size_t)kvh * S_LEN + s) * HD + chunk * 8) = t;
}

// ---- pre-pass 2: V [s][kv*hd] f32 -> Vtb [kv][hd][s] bf16 (transposed) ----
__global__ __launch_bounds__(256) void prep_v(const float* __restrict__ V,
                                              short* __restrict__ Vtb) {
    __shared__ short Ts[64][72];                 // 144B row stride: 16B-aligned
    int b = blockIdx.x;                          // 512 = kvh(8) x db(2) x sb(32)
    int sb = b & 31, db = (b >> 5) & 1, kvh = b >> 6;
    int t = threadIdx.x, r = t >> 2, c0 = (t & 3) * 16;

    const float* in = V + (size_t)(sb * 64 + r) * KSTR + kvh * HD + db * 64 + c0;
    f32x4 a0 = *(const f32x4*)in,        a1 = *(const f32x4*)(in + 4);
    f32x4 a2 = *(const f32x4*)(in + 8),  a3 = *(const f32x4*)(in + 12);
    u32x4 t0;
    t0[0] = cvt_pk_bf16(a0[0], a0[1]); t0[1] = cvt_pk_bf16(a0[2], a0[3]);
    t0[2] = cvt_pk_bf16(a1[0], a1[1]); t0[3] = cvt_pk_bf16(a1[2], a1[3]);
    *(u32x4*)&Ts[r][c0] = t0;
    t0[0] = cvt_pk_bf16(a2[0], a2[1]); t0[1] = cvt_pk_bf16(a2[2], a2[3]);
    t0[2] = cvt_pk_bf16(a3[0], a3[1]); t0[3] = cvt_pk_bf16(a3[2], a3[3]);
    *(u32x4*)&Ts[r][c0 + 8] = t0;
    __syncthreads();

    alignas(16) short tmp[16];
    #pragma unroll
    for (int j = 0; j < 16; ++j) tmp[j] = Ts[c0 + j][r];
    short* dst = Vtb + ((size_t)(kvh * HD + db * 64 + r)) * S_LEN + sb * 64 + c0;
    *(u32x4*)dst       = *(u32x4*)&tmp[0];
    *(u32x4*)(dst + 8) = *(u32x4*)&tmp[8];
}

// ---- main: 1 wave per block, 16 q-rows, fragments direct from bf16 ----
__global__ __launch_bounds__(64) void attn_fwd(
    const float* __restrict__ Q, const short* __restrict__ Kbf,
    const short* __restrict__ Vtb, const float* __restrict__ SL,
    float* __restrict__ O)
{
    const int bx  = blockIdx.x;
    const int h   = bx & (NHEADS - 1);
    const int qp  = (NQP - 1) - (bx >> 5);       // heavy q first
    const int kvh = h >> 2;
    const float slope  = SL[h];
    const float slope2 = slope * LOG2E;

    const int lane = threadIdx.x;                // 64-thread block = 1 wave
    const int l16  = lane & 15;
    const int lq   = lane >> 4;

    __shared__ short Ps[16 * P_STRIDE];          // wave-local P [q][k]

    const int qrow0 = qp * 16;

    // ---- Q fragments, scale*log2e folded in ----
    bf16x8 qf[4];
    {
        const float* qp_ = Q + (size_t)(qrow0 + l16) * QSTR + h * HD + lq * 8;
        #pragma unroll
        for (int d0 = 0; d0 < 4; ++d0) {
            f32x4 a = *(const f32x4*)(qp_ + d0 * 32);
            f32x4 b = *(const f32x4*)(qp_ + d0 * 32 + 4);
            u32x4 t;
            t[0] = cvt_pk_bf16(a[0] * QK_SCALE2, a[1] * QK_SCALE2);
            t[1] = cvt_pk_bf16(a[2] * QK_SCALE2, a[3] * QK_SCALE2);
            t[2] = cvt_pk_bf16(b[0] * QK_SCALE2, b[1] * QK_SCALE2);
            t[3] = cvt_pk_bf16(b[2] * QK_SCALE2, b[3] * QK_SCALE2);
            qf[d0] = as_bf16x8(t);
        }
    }
    bf16x8 onesf;
    #pragma unroll
    for (int j = 0; j < 8; ++j) onesf[j] = (short)0x3f80;

    f32x4 acc[8];
    #pragma unroll
    for (int t = 0; t < 8; ++t) acc[t] = (f32x4){0.f, 0.f, 0.f, 0.f};
    float m_i[4] = {-1e30f, -1e30f, -1e30f, -1e30f};
    float l_i[4] = {0.f, 0.f, 0.f, 0.f};

    float sq2[4];
    int   qri[4];
    #pragma unroll
    for (int i = 0; i < 4; ++i) {
        qri[i] = qrow0 + 4 * lq + i;
        sq2[i] = slope2 * (float)qri[i];
    }

    // ---- per-wave bounds: causal end + ALiBi start ----
    const int kbe = qrow0 + 16;                  // exclusive
    int kbs = 0;
    {
        float th = (float)qrow0 - 31.0f - 45.0f / slope;
        int t = (int)floorf(th);
        kbs = (t < 0) ? 0 : (((t >> 5) + 1) << 5);
    }

    const short* Kfb = Kbf + ((size_t)kvh * S_LEN + l16) * HD + lq * 8;
    const short* Vfb = Vtb + ((size_t)kvh * HD + l16) * S_LEN + lq * 8;

    // ---- prologue: first tile's K and V fragments in flight ----
    bf16x8 kf[8], vf[8];
    {
        const short* kp0 = Kfb + (size_t)kbs * HD;
        #pragma unroll
        for (int d0 = 0; d0 < 4; ++d0) {
            kf[d0]     = *(const bf16x8*)(kp0 + d0 * 32);
            kf[d0 + 4] = *(const bf16x8*)(kp0 + 16 * HD + d0 * 32);
        }
        #pragma unroll
        for (int nt = 0; nt < 8; ++nt)
            vf[nt] = *(const bf16x8*)(Vfb + (size_t)nt * 16 * S_LEN + kbs);
    }

    for (int kb = kbs; kb < kbe; kb += BK) {
        const bool has_next = (kb + BK) < kbe;

        // ---- QK^T (consumes kf) ----
        f32x4 sc0 = (f32x4){0.f,0.f,0.f,0.f};
        f32x4 sc1 = (f32x4){0.f,0.f,0.f,0.f};
        #pragma unroll
        for (int d0 = 0; d0 < 4; ++d0) {
            sc0 = __builtin_amdgcn_mfma_f32_16x16x32_bf16(qf[d0], kf[d0],     sc0, 0, 0, 0);
            sc1 = __builtin_amdgcn_mfma_f32_16x16x32_bf16(qf[d0], kf[d0 + 4], sc1, 0, 0, 0);
        }
        // ---- issue next K immediately (latency hides under softmax+PV) ----
        if (has_next) {
            const short* kp0 = Kfb + (size_t)(kb + BK) * HD;
            #pragma unroll
            for (int d0 = 0; d0 < 4; ++d0) {
                kf[d0]     = *(const bf16x8*)(kp0 + d0 * 32);
                kf[d0 + 4] = *(const bf16x8*)(kp0 + 16 * HD + d0 * 32);
            }
        }

        // ---- bias + causal (log2 domain) ----
        const int   kc0  = kb + l16, kc1 = kb + 16 + l16;
        const float kcf0 = (float)kc0, kcf1 = (float)kc1;
        float s0v[4], s1v[4], lm[4];
        bool need = false;
        #pragma unroll
        for (int i = 0; i < 4; ++i) {
            float s0 = (kc0 > qri[i]) ? -1e30f
                     : sc0[i] + __builtin_fmaf(slope2, kcf0, -sq2[i]);
            float s1 = (kc1 > qri[i]) ? -1e30f
                     : sc1[i] + __builtin_fmaf(slope2, kcf1, -sq2[i]);
            s0v[i] = s0; s1v[i] = s1;
            lm[i] = fmaxf(s0, s1);
            need = need || (lm[i] > m_i[i] + DTHR);
        }
        if (__any(need)) {
            #pragma unroll
            for (int i = 0; i < 4; ++i) {
                float rm = lm[i];
                rm = fmaxf(rm, __shfl_xor(rm, 1));
                rm = fmaxf(rm, __shfl_xor(rm, 2));
                rm = fmaxf(rm, __shfl_xor(rm, 4));
                rm = fmaxf(rm, __shfl_xor(rm, 8));
                if (rm > m_i[i] + DTHR) {
                    float alpha = exp2f(m_i[i] - rm);
                    m_i[i] = rm;
                    l_i[i] *= alpha;
                    #pragma unroll
                    for (int t = 0; t < 8; ++t) acc[t][i] *= alpha;
                }
            }
        }

        // ---- P = exp2(s - m), bf16 via wave-local LDS (layout C->A) ----
        #pragma unroll
        for (int i = 0; i < 4; ++i) {
            float p0 = exp2f(s0v[i] - m_i[i]);
            float p1 = exp2f(s1v[i] - m_i[i]);
            Ps[(4 * lq + i) * P_STRIDE + l16]      = f2bf(p0);
            Ps[(4 * lq + i) * P_STRIDE + 16 + l16] = f2bf(p1);
        }
        // wave-local DS fence (memory clobber orders the ds ops; no sched_barrier
        // so the scheduler can still pipeline across iterations)
        asm volatile("s_waitcnt lgkmcnt(0)" ::: "memory");
        bf16x8 pf = *(const bf16x8*)&Ps[l16 * P_STRIDE + lq * 8];

        // ---- row-sum via ones-MFMA, then PV (consumes vf) ----
        f32x4 sums = (f32x4){0.f,0.f,0.f,0.f};
        sums = __builtin_amdgcn_mfma_f32_16x16x32_bf16(pf, onesf, sums, 0, 0, 0);
        #pragma unroll
        for (int nt = 0; nt < 8; ++nt)
            acc[nt] = __builtin_amdgcn_mfma_f32_16x16x32_bf16(pf, vf[nt], acc[nt], 0, 0, 0);
        // ---- issue next V (latency hides under next QK+softmax) ----
        if (has_next) {
            #pragma unroll
            for (int nt = 0; nt < 8; ++nt)
                vf[nt] = *(const bf16x8*)(Vfb + (size_t)nt * 16 * S_LEN + kb + BK);
        }
        #pragma unroll
        for (int i = 0; i < 4; ++i) l_i[i] += sums[i];
    }

    // ---- epilogue ----
    #pragma unroll
    for (int i = 0; i < 4; ++i) {
        float rl = 1.0f / l_i[i];
        float* op = O + (size_t)qri[i] * QSTR + h * HD + l16;
        #pragma unroll
        for (int nt = 0; nt < 8; ++nt)
            op[nt * 16] = acc[nt][i] * rl;
    }
}

extern "C" void kernel_launch(void* const* d_in, const int* in_sizes, int n_in,
                              void* d_out, int out_size, void* d_ws, size_t ws_size,
                              hipStream_t stream) {
    const float* Q  = (const float*)d_in[0];
    const float* K  = (const float*)d_in[1];
    const float* V  = (const float*)d_in[2];
    const float* SL = (const float*)d_in[3];
    float* O = (float*)d_out;

    short* Kbf = (short*)d_ws;                                   // 4 MB
    short* Vtb = (short*)d_ws + (size_t)NKV * S_LEN * HD;        // 4 MB

    prep_k<<<dim3(1024), dim3(256), 0, stream>>>(K, Kbf);
    prep_v<<<dim3(512),  dim3(256), 0, stream>>>(V, Vtb);
    attn_fwd<<<dim3(NQP * NHEADS), dim3(64), 0, stream>>>(Q, Kbf, Vtb, SL, O);
}

// Round 10
// 102.319 us; speedup vs baseline: 6.3868x; 2.5051x over previous
//
#include <hip/hip_runtime.h>
#include <hip/hip_bf16.h>

#define S_LEN 2048
#define NHEADS 32
#define NKV 8
#define HD 128
#define QK_SCALE 0.08838834764831845f           // 1/sqrt(128)
#define LOG2E 1.4426950408889634f
#define QK_SCALE2 (QK_SCALE * LOG2E)            // folded into Q (log2 domain)
#define DTHR 11.5416f                           // defer-max threshold (8 nats in log2)

#define BQ 64                 // q rows per block
#define BK 32                 // kv rows per tile
#define NQT (S_LEN / BQ)      // 32 q tiles
#define QSTR (NHEADS * HD)    // 4096
#define KSTR (NKV * HD)       // 1024

#define K_STRIDE 136          // LDS row stride (shorts)
#define VT_STRIDE 40
#define P_STRIDE 40

typedef __attribute__((ext_vector_type(8))) short bf16x8;
typedef __attribute__((ext_vector_type(4))) float f32x4;
typedef __attribute__((ext_vector_type(4))) unsigned u32x4;
typedef __attribute__((ext_vector_type(2))) unsigned u32x2;

__device__ inline unsigned cvt_pk_bf16(float lo, float hi) {
    unsigned r;
    asm("v_cvt_pk_bf16_f32 %0, %1, %2" : "=v"(r) : "v"(lo), "v"(hi));
    return r;
}
__device__ inline bf16x8 as_bf16x8(u32x4 v) {
    union { u32x4 u; bf16x8 b; } c; c.u = v; return c.b;
}

__global__ __launch_bounds__(256) void attn_fwd(
    const float* __restrict__ Q, const float* __restrict__ K,
    const float* __restrict__ V, const float* __restrict__ SL,
    float* __restrict__ O)
{
    const int bx   = blockIdx.x;
    const int h    = bx & (NHEADS - 1);
    const int qt   = (NQT - 1) - (bx >> 5);     // heavy q-tiles dispatch first
    const int kvh  = h >> 2;
    const float slope  = SL[h];
    const float slope2 = slope * LOG2E;

    const int tid  = threadIdx.x;
    const int w    = tid >> 6;
    const int lane = tid & 63;
    const int l16  = lane & 15;
    const int lq   = lane >> 4;

    __shared__ short Ks[2][BK * K_STRIDE];     // double-buffered K [k][d]
    __shared__ short VTs[2][HD * VT_STRIDE];   // double-buffered V^T [d][k]
    __shared__ short Ps[4][16 * P_STRIDE];     // per-wave P [q][k]

    const int qrow0 = qt * BQ + w * 16;
    const int q     = qrow0 + l16;             // this lane's q row (swapped layout)

    // ---- Q fragment (B-operand now; same per-lane mapping as before) ----
    bf16x8 qf[4];
    {
        const float* qp = Q + (size_t)q * QSTR + h * HD + lq * 8;
        #pragma unroll
        for (int d0 = 0; d0 < 4; ++d0) {
            f32x4 a = *(const f32x4*)(qp + d0 * 32);
            f32x4 b = *(const f32x4*)(qp + d0 * 32 + 4);
            u32x4 t;
            t[0] = cvt_pk_bf16(a[0] * QK_SCALE2, a[1] * QK_SCALE2);
            t[1] = cvt_pk_bf16(a[2] * QK_SCALE2, a[3] * QK_SCALE2);
            t[2] = cvt_pk_bf16(b[0] * QK_SCALE2, b[1] * QK_SCALE2);
            t[3] = cvt_pk_bf16(b[2] * QK_SCALE2, b[3] * QK_SCALE2);
            qf[d0] = as_bf16x8(t);
        }
    }

    // acc holds O^T: acc[t][i] = O[q][t*16 + 4*lq + i]
    f32x4 acc[8];
    #pragma unroll
    for (int t = 0; t < 8; ++t) acc[t] = (f32x4){0.f, 0.f, 0.f, 0.f};
    float m_ = -1e30f, l_ = 0.f;               // per-lane scalars (one q per lane)

    const int kv_end = qt * BQ + BQ;
    int kb_start = 0;
    {   // ALiBi far-tile skip (weight <= e^-33 vs diagonal); kb_start <= qrow0 always
        float th = (float)(qt * BQ) - 31.0f - 45.0f / slope;
        int t = (int)floorf(th);
        kb_start = (t < 0) ? 0 : (((t >> 5) + 1) << 5);
    }

    // ---- staging thread mapping (identical to R4, proven) ----
    const int sr  = tid >> 4, scc = tid & 15;
    const int vd  = tid & 127, vrb = (tid >> 7) * 8;
    const float* Kbase = K + (size_t)kvh * HD + scc * 8;
    const float* Vbase = V + (size_t)kvh * HD + vd;

    float kr[2][8], vr[2][8];

    auto load_regs = [&](int kb) {
        #pragma unroll
        for (int s = 0; s < 2; ++s) {
            const float* kp = Kbase + (size_t)(kb + sr + s * 16) * KSTR;
            *(f32x4*)&kr[s][0] = *(const f32x4*)kp;
            *(f32x4*)&kr[s][4] = *(const f32x4*)(kp + 4);
        }
        #pragma unroll
        for (int s = 0; s < 2; ++s)
            #pragma unroll
            for (int j = 0; j < 8; ++j)
                vr[s][j] = Vbase[(size_t)(kb + vrb + s * 16 + j) * KSTR];
    };

    auto store_tile = [&](int b) {
        #pragma unroll
        for (int s = 0; s < 2; ++s) {
            u32x4 t;
            t[0] = cvt_pk_bf16(kr[s][0], kr[s][1]);
            t[1] = cvt_pk_bf16(kr[s][2], kr[s][3]);
            t[2] = cvt_pk_bf16(kr[s][4], kr[s][5]);
            t[3] = cvt_pk_bf16(kr[s][6], kr[s][7]);
            *(u32x4*)&Ks[b][(sr + s * 16) * K_STRIDE + scc * 8] = t;
        }
        #pragma unroll
        for (int s = 0; s < 2; ++s) {
            u32x4 t;
            t[0] = cvt_pk_bf16(vr[s][0], vr[s][1]);
            t[1] = cvt_pk_bf16(vr[s][2], vr[s][3]);
            t[2] = cvt_pk_bf16(vr[s][4], vr[s][5]);
            t[3] = cvt_pk_bf16(vr[s][6], vr[s][7]);
            *(u32x4*)&VTs[b][vd * VT_STRIDE + vrb + s * 16] = t;
        }
    };

    load_regs(kb_start);
    store_tile(0);
    int cur = 0;

    for (int kb = kb_start; kb < kv_end; kb += BK) {
        // one barrier per tile; vmcnt NOT drained (prefetch spans barrier)
        asm volatile("s_waitcnt lgkmcnt(0)\n\ts_barrier" ::: "memory");

        const bool has_next = (kb + BK) < kv_end;
        if (has_next) load_regs(kb + BK);

        const bool live = (kb <= qrow0 + 15) &&
                          (slope * (float)(qrow0 - kb - 31) < 45.0f);
        if (live) {
            const short* Kc = &Ks[cur][0];
            const short* Vc = &VTs[cur][0];

            // ---- S^T = K·Q^T : A = K rows (k), B = Q (col = q = l16) ----
            f32x4 sc0 = (f32x4){0.f,0.f,0.f,0.f};   // k = kb + 4*lq + i
            f32x4 sc1 = (f32x4){0.f,0.f,0.f,0.f};   // k = kb + 16 + 4*lq + i
            #pragma unroll
            for (int d0 = 0; d0 < 4; ++d0) {
                bf16x8 kf0 = *(const bf16x8*)&Kc[l16 * K_STRIDE + d0 * 32 + lq * 8];
                bf16x8 kf1 = *(const bf16x8*)&Kc[(16 + l16) * K_STRIDE + d0 * 32 + lq * 8];
                sc0 = __builtin_amdgcn_mfma_f32_16x16x32_bf16(kf0, qf[d0], sc0, 0, 0, 0);
                sc1 = __builtin_amdgcn_mfma_f32_16x16x32_bf16(kf1, qf[d0], sc1, 0, 0, 0);
            }

            // ---- bias + causal, all per-lane (q fixed = l16 col) ----
            const int kq0 = kb + 4 * lq - q;         // k - q at subtile A, i=0
            float s[8];
            #pragma unroll
            for (int i = 0; i < 4; ++i) {
                int d0i = kq0 + i, d1i = kq0 + 16 + i;
                float b0 = __builtin_fmaf(slope2, (float)d0i, sc0[i]);
                float b1 = __builtin_fmaf(slope2, (float)d1i, sc1[i]);
                s[i]     = (d0i > 0) ? -1e30f : b0;
                s[i + 4] = (d1i > 0) ? -1e30f : b1;
            }

            // ---- per-q max: 7 fmax + 2 shuffles (lanes l16, +16, +32, +48) ----
            float rm = fmaxf(fmaxf(fmaxf(s[0], s[1]), fmaxf(s[2], s[3])),
                             fmaxf(fmaxf(s[4], s[5]), fmaxf(s[6], s[7])));
            rm = fmaxf(rm, __shfl_xor(rm, 16));
            rm = fmaxf(rm, __shfl_xor(rm, 32));

            bool need = (rm > m_ + DTHR);
            if (__any(need)) {
                float mn    = need ? rm : m_;
                float alpha = exp2f(m_ - mn);        // 1.0 when !need
                m_ = mn;
                l_ *= alpha;
                #pragma unroll
                for (int t = 0; t < 8; ++t) {
                    acc[t][0] *= alpha; acc[t][1] *= alpha;
                    acc[t][2] *= alpha; acc[t][3] *= alpha;
                }
            }

            // ---- p = exp2(s - m); sum; pack ----
            float p[8];
            #pragma unroll
            for (int j = 0; j < 8; ++j) p[j] = exp2f(s[j] - m_);
            float ts = ((p[0] + p[1]) + (p[2] + p[3])) +
                       ((p[4] + p[5]) + (p[6] + p[7]));
            ts += __shfl_xor(ts, 16);
            ts += __shfl_xor(ts, 32);
            l_ += ts;

            u32x2 pa, pb;
            pa[0] = cvt_pk_bf16(p[0], p[1]); pa[1] = cvt_pk_bf16(p[2], p[3]);
            pb[0] = cvt_pk_bf16(p[4], p[5]); pb[1] = cvt_pk_bf16(p[6], p[7]);

            // ---- P[q][k] to LDS: two b64 writes, one b128 read ----
            short* PsW = &Ps[w][0];
            *(u32x2*)&PsW[l16 * P_STRIDE + 4 * lq]      = pa;  // k = 4lq..4lq+3
            *(u32x2*)&PsW[l16 * P_STRIDE + 16 + 4 * lq] = pb;  // k = 16+4lq..
            asm volatile("s_waitcnt lgkmcnt(0)" ::: "memory");
            bf16x8 pf = *(const bf16x8*)&PsW[l16 * P_STRIDE + lq * 8]; // k=8lq..+7

            // ---- O^T += V^T · P^T (A-operand reads identical to R4's) ----
            #pragma unroll
            for (int nt = 0; nt < 8; ++nt) {
                bf16x8 vf = *(const bf16x8*)&Vc[(nt * 16 + l16) * VT_STRIDE + lq * 8];
                acc[nt] = __builtin_amdgcn_mfma_f32_16x16x32_bf16(vf, pf, acc[nt], 0, 0, 0);
            }
        }

        if (has_next) store_tile(cur ^ 1);
        cur ^= 1;
    }

    // ---- epilogue: acc[t] = O[q][t*16 + 4lq .. +3], contiguous f32x4 ----
    {
        float rl = 1.0f / l_;
        float* op = O + (size_t)q * QSTR + h * HD + 4 * lq;
        #pragma unroll
        for (int nt = 0; nt < 8; ++nt) {
            f32x4 o = acc[nt];
            o[0] *= rl; o[1] *= rl; o[2] *= rl; o[3] *= rl;
            *(f32x4*)(op + nt * 16) = o;
        }
    }
}

extern "C" void kernel_launch(void* const* d_in, const int* in_sizes, int n_in,
                              void* d_out, int out_size, void* d_ws, size_t ws_size,
                              hipStream_t stream) {
    const float* Q  = (const float*)d_in[0];
    const float* K  = (const float*)d_in[1];
    const float* V  = (const float*)d_in[2];
    const float* SL = (const float*)d_in[3];
    float* O = (float*)d_out;

    dim3 grid(NQT * NHEADS);
    dim3 block(256);
    attn_fwd<<<grid, block, 0, stream>>>(Q, K, V, SL, O);
}